// Round 1
// baseline (515.019 us; speedup 1.0000x reference)
//
#include <hip/hip_runtime.h>
#include <hip/hip_bf16.h>

// Problem constants (from reference): B=64, Cin=64, Cout=64, F=32, K=3, pad=1
#define BB 64
#define CC 64
#define OO 64
#define FF 32
#define SPATIAL (FF*FF)          // 1024
#define WSTR (CC*SPATIAL*9)      // per-o weight stride = 64*1024*9 = 589824
#define BN_N (BB*SPATIAL)        // 65536 elements per channel for BN stats

// ---------------------------------------------------------------------------
// Kernel 1: locally-connected conv + bias -> y (written to d_out)
// Thread tile: 8 b  x 4 o accumulators at fixed (i,j).
// Block: 256 threads = 32 lanes (j) x 8 groups (b-tile). Grid: (i=32, o-tile=16).
// Each block owns a disjoint weight slab [o0..o0+3][*][i][*][*] -> weight read
// exactly once from HBM, coalesced enough (9-float runs consumed by uv loop).
// ---------------------------------------------------------------------------
__global__ __launch_bounds__(256, 2)
void ll_conv(const float* __restrict__ x, const float* __restrict__ wgt,
             const float* __restrict__ bias, float* __restrict__ y) {
  const int j  = threadIdx.x & 31;
  const int ty = threadIdx.x >> 5;      // 0..7 -> b-tile
  const int i  = blockIdx.x;            // 0..31
  const int o0 = blockIdx.y * 4;        // 4 o's per block
  const int b0 = ty * 8;                // 8 b's per thread

  float acc[8][4];
#pragma unroll
  for (int bi = 0; bi < 8; ++bi)
#pragma unroll
    for (int oi = 0; oi < 4; ++oi) acc[bi][oi] = 0.f;

  const int ij9 = (i * FF + j) * 9;
  const float* wbase = wgt + (size_t)o0 * WSTR + ij9;     // + c*9216 + u*3+v
  const float* xbase = x + (size_t)b0 * (CC * SPATIAL);   // + bi*CC*SPATIAL + c*1024 + h*32 + w

  for (int c = 0; c < CC; ++c) {
    const float* wc = wbase + c * (SPATIAL * 9);
    const float* xc = xbase + c * SPATIAL;
#pragma unroll
    for (int u = 0; u < 3; ++u) {
      const int h = i + u - 1;
      if (h < 0 || h >= FF) continue;   // uniform across block (i is uniform)
#pragma unroll
      for (int v = 0; v < 3; ++v) {
        const int wj = j + v - 1;
        const bool ok = (wj >= 0) && (wj < FF);   // per-lane edge predicate
        float wv[4];
#pragma unroll
        for (int oi = 0; oi < 4; ++oi)
          wv[oi] = wc[oi * WSTR + u * 3 + v];
        const float* xr = xc + h * FF + wj;
        float xv[8];
#pragma unroll
        for (int bi = 0; bi < 8; ++bi)
          xv[bi] = ok ? xr[bi * (CC * SPATIAL)] : 0.f;
#pragma unroll
        for (int bi = 0; bi < 8; ++bi)
#pragma unroll
          for (int oi = 0; oi < 4; ++oi)
            acc[bi][oi] = fmaf(xv[bi], wv[oi], acc[bi][oi]);
      }
    }
  }

  // bias + store y[b,o,i,j]
  const int ij = i * FF + j;
#pragma unroll
  for (int oi = 0; oi < 4; ++oi) {
    const float bv = bias[(o0 + oi) * SPATIAL + ij];
#pragma unroll
    for (int bi = 0; bi < 8; ++bi) {
      y[(size_t)(b0 + bi) * (OO * SPATIAL) + (o0 + oi) * SPATIAL + ij] =
          acc[bi][oi] + bv;
    }
  }
}

// ---------------------------------------------------------------------------
// Kernel 2: per-channel BN statistics (training mode: over B,H,W).
// 64 blocks (one per o). Double accumulation for safety. Writes scale/shift
// pairs into ws[o*2], ws[o*2+1].
// ---------------------------------------------------------------------------
__global__ __launch_bounds__(256)
void bn_stats(const float* __restrict__ y, const float* __restrict__ gamma,
              const float* __restrict__ beta, float* __restrict__ ss) {
  const int o = blockIdx.x;
  double s = 0.0, s2 = 0.0;
  for (int idx = threadIdx.x; idx < BN_N; idx += 256) {
    const int b  = idx >> 10;         // / 1024
    const int sp = idx & 1023;
    const float v = y[(size_t)b * (OO * SPATIAL) + o * SPATIAL + sp];
    s  += (double)v;
    s2 += (double)v * (double)v;
  }
  __shared__ double sh0[256];
  __shared__ double sh1[256];
  sh0[threadIdx.x] = s;
  sh1[threadIdx.x] = s2;
  __syncthreads();
  for (int off = 128; off > 0; off >>= 1) {
    if (threadIdx.x < off) {
      sh0[threadIdx.x] += sh0[threadIdx.x + off];
      sh1[threadIdx.x] += sh1[threadIdx.x + off];
    }
    __syncthreads();
  }
  if (threadIdx.x == 0) {
    const double inv_n = 1.0 / (double)BN_N;
    const double mean = sh0[0] * inv_n;
    const double var  = sh1[0] * inv_n - mean * mean;
    const double rstd = 1.0 / sqrt(var + 1e-5);
    const float g = gamma[o];
    const float sc = (float)((double)g * rstd);
    ss[o * 2]     = sc;
    ss[o * 2 + 1] = beta[o] - (float)mean * sc;
  }
}

// ---------------------------------------------------------------------------
// Kernel 3: y = relu(y*scale[o] + shift[o]), in place on d_out, float4.
// ---------------------------------------------------------------------------
__global__ __launch_bounds__(256)
void bn_apply(float* __restrict__ y, const float* __restrict__ ss) {
  const size_t idx = ((size_t)blockIdx.x * 256 + threadIdx.x) * 4;
  const int o = (int)((idx >> 10) & (OO - 1));
  const float sc = ss[o * 2];
  const float sh = ss[o * 2 + 1];
  float4 v = *reinterpret_cast<const float4*>(y + idx);
  v.x = fmaxf(fmaf(v.x, sc, sh), 0.f);
  v.y = fmaxf(fmaf(v.y, sc, sh), 0.f);
  v.z = fmaxf(fmaf(v.z, sc, sh), 0.f);
  v.w = fmaxf(fmaf(v.w, sc, sh), 0.f);
  *reinterpret_cast<float4*>(y + idx) = v;
}

// ---------------------------------------------------------------------------
extern "C" void kernel_launch(void* const* d_in, const int* in_sizes, int n_in,
                              void* d_out, int out_size, void* d_ws, size_t ws_size,
                              hipStream_t stream) {
  const float* x    = (const float*)d_in[0];
  const float* wgt  = (const float*)d_in[1];
  const float* bias = (const float*)d_in[2];
  const float* gamma = (const float*)d_in[3];
  const float* beta  = (const float*)d_in[4];
  float* y  = (float*)d_out;
  float* ss = (float*)d_ws;   // 128 floats: per-channel scale/shift

  // conv + bias
  dim3 grid1(FF, OO / 4);   // (i, o-tile) = (32, 16)
  ll_conv<<<grid1, 256, 0, stream>>>(x, wgt, bias, y);

  // BN stats
  bn_stats<<<OO, 256, 0, stream>>>(y, gamma, beta, ss);

  // normalize + relu
  const int total4 = (BB * OO * SPATIAL) / 4;       // 1048576
  bn_apply<<<total4 / 256, 256, 0, stream>>>(y, ss);
}

// Round 2
// 368.827 us; speedup vs baseline: 1.3964x; 1.3964x over previous
//
#include <hip/hip_runtime.h>
#include <hip/hip_bf16.h>

#define BB 64
#define CC 64
#define OO 64
#define FF 32
#define SPATIAL 1024
#define WSTR 589824       // o stride in weight (C*F*F*K*K)
#define CSTR 9216         // c stride in weight (F*F*K*K)

typedef short s16x8 __attribute__((ext_vector_type(8)));
typedef float f32x16 __attribute__((ext_vector_type(16)));

__device__ __forceinline__ unsigned short f2bf(float f) {
  unsigned int u = __float_as_uint(f);
  u = (u + 0x7fffu + ((u >> 16) & 1u)) >> 16;
  return (unsigned short)u;
}

// ---------------------------------------------------------------------------
// Conv as 1024 independent GEMMs: M=64(b) x N=64(o) x K=576 (padded to 1024).
// One block per (i,j). 4 waves = 4 C-quadrants (32b x 32o) via 32x32x16 MFMA.
// k' = c*16 + uv (uv 0..8 real, 9..15 zero). c-chunks of 16 -> 4 chunks.
// LDS: A[64][256] + B[64][256] bf16 = 64 KB exactly, XOR bit-4 swizzle
// (row&7)<<4 on byte offsets (write and read) to avoid stride-512B bank
// pathology on ds_read_b128.
// Output: y_tmp[ij][b][o] (position-major) -> per-block contiguous stores.
// ---------------------------------------------------------------------------
__global__ __launch_bounds__(256)
void ll_conv_mfma(const float* __restrict__ x, const float* __restrict__ wgt,
                  const float* __restrict__ bias, float* __restrict__ y_tmp) {
  __shared__ alignas(16) short A_lds[64 * 256];
  __shared__ alignas(16) short B_lds[64 * 256];

  const int bid = blockIdx.x;
  const int pos = (bid & 7) * 128 + (bid >> 3);   // XCD-contiguous swizzle
  const int i = pos >> 5, j = pos & 31;
  const int ij = pos;
  const int tid = threadIdx.x;
  const int lane = tid & 63;
  const int w = tid >> 6;                 // wave 0..3
  const int b0 = (w >> 1) * 32;           // b-half
  const int o0 = (w & 1) * 32;            // o-half
  const int lr = lane & 31;
  const int hi = lane >> 5;               // k-subgroup select

  f32x16 acc = {};

  for (int chunk = 0; chunk < 4; ++chunk) {
    const int c0 = chunk * 16;
    __syncthreads();   // protect previous chunk's reads before overwrite

    // ---- stage A (patches) and B (weight): 1024 (row, c') pairs each ----
    for (int q = 0; q < 4; ++q) {
      const int pair = tid + q * 256;
      const int r  = pair >> 4;     // b for A, o for B
      const int cc = pair & 15;     // c' within chunk
      const int c  = c0 + cc;
      const int swz = (r & 7) << 4;
      const int byte0 = (cc * 32) ^ swz;
      const int byte1 = (cc * 32 + 16) ^ swz;

      // A: x patch, k = uv (0..8), zero-pad 9..15
      {
        float v[16];
#pragma unroll
        for (int t = 0; t < 16; ++t) v[t] = 0.f;
        const float* xb = x + ((size_t)r * CC + c) * SPATIAL;
#pragma unroll
        for (int u = 0; u < 3; ++u) {
          const int h = i + u - 1;
          if (h >= 0 && h < FF) {
#pragma unroll
            for (int vv = 0; vv < 3; ++vv) {
              const int wj = j + vv - 1;
              if (wj >= 0 && wj < FF) v[u * 3 + vv] = xb[h * FF + wj];
            }
          }
        }
        s16x8 lo, hig;
#pragma unroll
        for (int t = 0; t < 8; ++t) lo[t] = (short)f2bf(v[t]);
#pragma unroll
        for (int t = 0; t < 8; ++t) hig[t] = (short)f2bf(v[8 + t]);
        *(s16x8*)&A_lds[r * 256 + (byte0 >> 1)] = lo;
        *(s16x8*)&A_lds[r * 256 + (byte1 >> 1)] = hig;
      }
      // B: weight run of 9, zero-pad
      {
        float v[16];
#pragma unroll
        for (int t = 0; t < 16; ++t) v[t] = 0.f;
        const float* wp = wgt + (size_t)r * WSTR + (size_t)c * CSTR + (size_t)ij * 9;
#pragma unroll
        for (int t = 0; t < 9; ++t) v[t] = wp[t];
        s16x8 lo, hig;
#pragma unroll
        for (int t = 0; t < 8; ++t) lo[t] = (short)f2bf(v[t]);
#pragma unroll
        for (int t = 0; t < 8; ++t) hig[t] = (short)f2bf(v[8 + t]);
        *(s16x8*)&B_lds[r * 256 + (byte0 >> 1)] = lo;
        *(s16x8*)&B_lds[r * 256 + (byte1 >> 1)] = hig;
      }
    }
    __syncthreads();

    // ---- compute: 16 k-steps of 16 ----
    const int arow = b0 + lr;
    const int brow = o0 + lr;
    const int aswz = (arow & 7) << 4;
    const int bswz = (brow & 7) << 4;
#pragma unroll
    for (int ks = 0; ks < 16; ++ks) {
      const int kbyte = ks * 32 + (hi << 4);
      const s16x8 av = *(const s16x8*)&A_lds[arow * 256 + ((kbyte ^ aswz) >> 1)];
      const s16x8 bv = *(const s16x8*)&B_lds[brow * 256 + ((kbyte ^ bswz) >> 1)];
      acc = __builtin_amdgcn_mfma_f32_32x32x16_bf16(av, bv, acc, 0, 0, 0);
    }
  }

  // ---- epilogue: y_tmp[ij][b][o] = acc + bias[o][ij] ----
  const int col = o0 + lr;                   // o  (C/D: col = lane&31)
  const float bv = bias[(size_t)col * SPATIAL + ij];
  const int rbase = b0 + 4 * hi;             // C/D: row = (reg&3)+8*(reg>>2)+4*hi
#pragma unroll
  for (int rg = 0; rg < 16; ++rg) {
    const int brow = rbase + (rg & 3) + 8 * (rg >> 2);
    y_tmp[((size_t)ij * 64 + brow) * 64 + col] = acc[rg] + bv;
  }
}

// ---------------------------------------------------------------------------
// BN phase 1: partial sums per (block, o). 256 blocks x 256 rows each.
// y_tmp rows R = ij*64 + b, 64 o's per row (coalesced).
// ---------------------------------------------------------------------------
__global__ __launch_bounds__(256)
void bn_stats1(const float* __restrict__ yt, double* __restrict__ psum,
               double* __restrict__ psq) {
  const int t = threadIdx.x;
  const int o = t & 63, rg = t >> 6;
  const int rend = blockIdx.x * 256 + 256;
  double s = 0.0, s2 = 0.0;
  for (int r = blockIdx.x * 256 + rg; r < rend; r += 4) {
    const float v = yt[(size_t)r * 64 + o];
    s += (double)v;
    s2 += (double)v * (double)v;
  }
  __shared__ double shd[2][4][64];
  shd[0][rg][o] = s;
  shd[1][rg][o] = s2;
  __syncthreads();
  if (rg == 0) {
    double ts = 0.0, tq = 0.0;
#pragma unroll
    for (int g = 0; g < 4; ++g) { ts += shd[0][g][o]; tq += shd[1][g][o]; }
    psum[blockIdx.x * 64 + o] = ts;
    psq[blockIdx.x * 64 + o]  = tq;
  }
}

// ---------------------------------------------------------------------------
// BN phase 2: reduce 256 partials per o -> scale/shift.
// ---------------------------------------------------------------------------
__global__ __launch_bounds__(256)
void bn_finalize(const double* __restrict__ psum, const double* __restrict__ psq,
                 const float* __restrict__ gamma, const float* __restrict__ beta,
                 float* __restrict__ ss) {
  const int t = threadIdx.x;
  const int o = t & 63, pg = t >> 6;
  double s = 0.0, q = 0.0;
  for (int p = pg; p < 256; p += 4) {
    s += psum[p * 64 + o];
    q += psq[p * 64 + o];
  }
  __shared__ double shd[2][4][64];
  shd[0][pg][o] = s;
  shd[1][pg][o] = q;
  __syncthreads();
  if (pg == 0) {
    double S = 0.0, Q = 0.0;
#pragma unroll
    for (int g = 0; g < 4; ++g) { S += shd[0][g][o]; Q += shd[1][g][o]; }
    const double inv_n = 1.0 / 65536.0;
    const double mean = S * inv_n;
    const double var = Q * inv_n - mean * mean;
    const double rstd = 1.0 / sqrt(var + 1e-5);
    const float sc = (float)((double)gamma[o] * rstd);
    ss[o * 2] = sc;
    ss[o * 2 + 1] = beta[o] - (float)(mean * (double)sc);
  }
}

// ---------------------------------------------------------------------------
// Apply + transpose: y_tmp[ij][b][o] -> out[b][o][ij] with scale/shift+relu.
// Block: one b x 64 ij. Reads coalesced along o; writes float4 along ij.
// ---------------------------------------------------------------------------
__global__ __launch_bounds__(256)
void bn_apply_t(const float* __restrict__ yt, const float* __restrict__ ss,
                float* __restrict__ out) {
  const int b = blockIdx.x >> 4;
  const int ij0 = (blockIdx.x & 15) * 64;
  __shared__ float tile[64][65];
  const int t = threadIdx.x;
  {
    const int o = t & 63;
    const int g = t >> 6;
#pragma unroll
    for (int q = 0; q < 16; ++q) {
      const int ijp = g * 16 + q;
      tile[ijp][o] = yt[((size_t)(ij0 + ijp) * 64 + b) * 64 + o];
    }
  }
  __syncthreads();
  {
    const int o = t >> 2;
    const int seg = t & 3;
    const float sc = ss[o * 2], sh = ss[o * 2 + 1];
    float* op = out + ((size_t)b * 64 + o) * SPATIAL + ij0;
#pragma unroll
    for (int rep = 0; rep < 4; ++rep) {
      const int ijp = seg * 16 + rep * 4;
      float4 v;
      v.x = fmaxf(fmaf(tile[ijp + 0][o], sc, sh), 0.f);
      v.y = fmaxf(fmaf(tile[ijp + 1][o], sc, sh), 0.f);
      v.z = fmaxf(fmaf(tile[ijp + 2][o], sc, sh), 0.f);
      v.w = fmaxf(fmaf(tile[ijp + 3][o], sc, sh), 0.f);
      *(float4*)(op + ijp) = v;
    }
  }
}

// ---------------------------------------------------------------------------
extern "C" void kernel_launch(void* const* d_in, const int* in_sizes, int n_in,
                              void* d_out, int out_size, void* d_ws, size_t ws_size,
                              hipStream_t stream) {
  const float* x     = (const float*)d_in[0];
  const float* wgt   = (const float*)d_in[1];
  const float* bias  = (const float*)d_in[2];
  const float* gamma = (const float*)d_in[3];
  const float* beta  = (const float*)d_in[4];

  float* yt = (float*)d_ws;                                   // 16.78 MB
  double* psum = (double*)((char*)d_ws + 16777216);           // 128 KB
  double* psq  = psum + 256 * 64;                             // 128 KB
  float* ss    = (float*)(psq + 256 * 64);                    // 512 B

  ll_conv_mfma<<<1024, 256, 0, stream>>>(x, wgt, bias, yt);
  bn_stats1<<<256, 256, 0, stream>>>(yt, psum, psq);
  bn_finalize<<<1, 256, 0, stream>>>(psum, psq, gamma, beta, ss);
  bn_apply_t<<<1024, 256, 0, stream>>>(yt, ss, (float*)d_out);
}